// Round 5
// baseline (681.128 us; speedup 1.0000x reference)
//
#include <hip/hip_runtime.h>
#include <math.h>

// Kalman filter. Covariance trajectory (P_t, K_t) is batch-independent.
//   Kernel 1 (traj): 1 block, fp64. Gauss-Jordan on [S | HP] done entirely
//     in wave-0 registers via __shfl (no barriers/LDS in pivot loop),
//     yielding K^T = S^{-1} HP directly. 4 barriers/step. Emits K_t (fp32).
//   Kernel 2 (mk):   T blocks, M_t = (I - K_t H) F (fp32).
//   Kernel 3 (batch): barrier-free, LDS-free; one batch per 32-lane half-wave;
//     x exchanged via __shfl; M/K rows loaded to registers (L1-shared).

#define S_DIM 32
#define O_DIM 16
#define MK_STRIDE 1536   // per step: 1024 floats M + 512 floats K

// ---------------- Kernel 1: shared trajectory (fp64, 1 block) ----------------
__global__ __launch_bounds__(256) void traj_kernel(
    const float* __restrict__ cov0,  // (B,32,32) -> batch 0
    const float* __restrict__ Fm,    // (32,32)
    const float* __restrict__ Hm,    // (16,32)
    const float* __restrict__ Qm,    // (32,32)
    const float* __restrict__ Rm,    // (16,16)
    float* __restrict__ wsMK,        // (T,1536)
    int T)
{
    __shared__ double P  [S_DIM*33];
    __shared__ double Fs [S_DIM*33];
    __shared__ double Qs [S_DIM*33];
    __shared__ double Hs [O_DIM*33];
    __shared__ double Rs [O_DIM*17];
    __shared__ double HP [O_DIM*33];
    __shared__ double Ag [O_DIM*49];  // augmented [S(16) | HP(32)] stride 49
    __shared__ double KT [O_DIM*33];  // K^T (16x32)
    __shared__ double Tp [S_DIM*33];  // temp for general-F predict
    __shared__ int notId;

    const int tid = threadIdx.x;

    for (int i = tid; i < S_DIM*S_DIM; i += 256) {
        int r = i >> 5, c = i & 31;
        P [r*33+c] = (double)cov0[i];
        Fs[r*33+c] = (double)Fm[i];
        Qs[r*33+c] = (double)Qm[i];
    }
    for (int i = tid; i < O_DIM*S_DIM; i += 256) {
        int r = i >> 5, c = i & 31;
        Hs[r*33+c] = (double)Hm[i];
    }
    for (int i = tid; i < O_DIM*O_DIM; i += 256) {
        int r = i >> 4, c = i & 15;
        Rs[r*17+c] = (double)Rm[i];
    }
    if (tid == 0) notId = 0;
    __syncthreads();

    {   // F == I detection (block-uniform)
        bool bad = false;
        for (int i = tid; i < S_DIM*S_DIM; i += 256) {
            int r = i >> 5, c = i & 31;
            if (Fs[r*33+c] != ((r == c) ? 1.0 : 0.0)) bad = true;
        }
        if (bad) notId = 1;
    }
    __syncthreads();
    const bool fId = (notId == 0);

    // For F==I, fold predict into the update: keep P as P_pred = P_post + Q.
    if (fId) {
        for (int i = tid; i < S_DIM*S_DIM; i += 256) {
            int r = i >> 5, c = i & 31;
            P[r*33+c] += Qs[r*33+c];
        }
    }
    __syncthreads();

    for (int t = 0; t < T; ++t) {
        // ---- general-F predict: P = F P F^T + Q (skipped when F==I) ----
        if (!fId) {
            for (int i = tid; i < S_DIM*S_DIM; i += 256) {
                int r = i >> 5, c = i & 31;
                double a = 0.0;
                for (int k = 0; k < S_DIM; ++k) a += Fs[r*33+k]*P[k*33+c];
                Tp[r*33+c] = a;
            }
            __syncthreads();
            for (int i = tid; i < S_DIM*S_DIM; i += 256) {
                int r = i >> 5, c = i & 31;
                double a = Qs[r*33+c];
                for (int k = 0; k < S_DIM; ++k) a += Tp[r*33+k]*Fs[c*33+k];
                P[r*33+c] = a;
            }
            __syncthreads();
        }

        // ---- HP = H * P_pred (16x32), 2 elements/thread ----
        {
            int i0 = tid, i1 = tid + 256;
            int r0 = i0 >> 5, c0 = i0 & 31;
            int r1 = i1 >> 5, c1 = i1 & 31;
            double a0 = 0.0, a1 = 0.0;
            for (int k = 0; k < S_DIM; ++k) {
                a0 += Hs[r0*33+k]*P[k*33+c0];
                a1 += Hs[r1*33+k]*P[k*33+c1];
            }
            HP[r0*33+c0] = a0;
            HP[r1*33+c1] = a1;
        }
        __syncthreads();

        // ---- Ag = [S | HP], S = HP H^T + R (16x48), 3 elements/thread ----
        for (int i = tid; i < O_DIM*48; i += 256) {
            int r = i / 48, c = i % 48;
            double v;
            if (c < O_DIM) {
                double a = Rs[r*17+c];
                for (int k = 0; k < S_DIM; ++k) a += HP[r*33+k]*Hs[c*33+k];
                v = a;
            } else {
                v = HP[r*33 + (c - O_DIM)];
            }
            Ag[r*49+c] = v;
        }
        __syncthreads();

        // ---- wave-0: register GJ on [S | HP] -> K^T = S^{-1} HP ----
        if (tid < 64) {
            const int lane = tid;
            const int r = lane & 15;        // row 0..15
            const int g = lane >> 4;        // col group 0..3 (12 cols each)
            double a[12];
            #pragma unroll
            for (int j = 0; j < 12; ++j) a[j] = Ag[r*49 + g*12 + j];

            #pragma unroll
            for (int p = 0; p < O_DIM; ++p) {
                const int pe = p % 12;             // compile-time per unroll
                const int pgBase = 16 * (p / 12);  // lane group holding col p
                // column p value for my row, and the pivot diagonal
                double colv = __shfl(a[pe], (lane & 15) + pgBase, 64);
                double app  = __shfl(a[pe], p + pgBase, 64);
                double pinv = 1.0 / app;
                // pivot row, my 12 columns
                double rowv[12];
                #pragma unroll
                for (int j = 0; j < 12; ++j)
                    rowv[j] = __shfl(a[j], p + (lane & 48), 64);
                const bool isP = (r == p);
                #pragma unroll
                for (int j = 0; j < 12; ++j) {
                    double sc = rowv[j] * pinv;
                    a[j] = isP ? sc : fma(-colv, sc, a[j]);
                }
            }
            // write back K^T (cols 16..47 of the augmented system)
            #pragma unroll
            for (int j = 0; j < 12; ++j) {
                int col = g*12 + j;
                if (col >= 16) KT[r*33 + (col - 16)] = a[j];
            }
        }
        __syncthreads();

        // ---- emit K (fp32, 32x16 row-major) + P = P - K^T' HP (+Q if F==I) ----
        {
            float* MK = wsMK + (long)t * MK_STRIDE;
            int i0 = tid, i1 = tid + 256;
            MK[1024 + i0] = (float)KT[(i0 & 15)*33 + (i0 >> 4)];
            MK[1024 + i1] = (float)KT[(i1 & 15)*33 + (i1 >> 4)];
            for (int i = tid; i < S_DIM*S_DIM; i += 256) {
                int r = i >> 5, c = i & 31;
                double acc = 0.0;
                for (int k = 0; k < O_DIM; ++k) acc += KT[k*33+r]*HP[k*33+c];
                double v = P[r*33+c] - acc;
                if (fId) v += Qs[r*33+c];
                P[r*33+c] = v;
            }
        }
        __syncthreads();
    }
}

// ---------------- Kernel 2: M_t = (I - K_t H) F, fp32, T blocks ----------------
__global__ __launch_bounds__(256) void mk_kernel(
    const float* __restrict__ Fm,    // (32,32)
    const float* __restrict__ Hm,    // (16,32)
    float* __restrict__ wsMK,        // (T,1536): K at +1024 (in), M at +0 (out)
    int T)
{
    __shared__ float Kl[S_DIM*17];
    __shared__ float Hl[O_DIM*33];
    __shared__ float Fl[S_DIM*33];
    __shared__ float Wl[S_DIM*33];
    __shared__ int notId;

    const int tid = threadIdx.x;
    const int t   = blockIdx.x;
    float* MK = wsMK + (long)t * MK_STRIDE;

    for (int i = tid; i < S_DIM*O_DIM; i += 256)
        Kl[(i >> 4)*17 + (i & 15)] = MK[1024 + i];
    for (int i = tid; i < O_DIM*S_DIM; i += 256)
        Hl[(i >> 5)*33 + (i & 31)] = Hm[i];
    for (int i = tid; i < S_DIM*S_DIM; i += 256)
        Fl[(i >> 5)*33 + (i & 31)] = Fm[i];
    if (tid == 0) notId = 0;
    __syncthreads();
    {
        bool bad = false;
        for (int i = tid; i < S_DIM*S_DIM; i += 256) {
            int r = i >> 5, c = i & 31;
            if (Fl[r*33+c] != ((r == c) ? 1.0f : 0.0f)) bad = true;
        }
        if (bad) notId = 1;
    }
    __syncthreads();
    const bool fId = (notId == 0);

    if (fId) {
        for (int i = tid; i < S_DIM*S_DIM; i += 256) {
            int r = i >> 5, c = i & 31;
            float a = (r == c) ? 1.0f : 0.0f;
            for (int k = 0; k < O_DIM; ++k) a -= Kl[r*17+k]*Hl[k*33+c];
            MK[i] = a;
        }
    } else {
        for (int i = tid; i < S_DIM*S_DIM; i += 256) {
            int r = i >> 5, c = i & 31;
            float a = (r == c) ? 1.0f : 0.0f;
            for (int k = 0; k < O_DIM; ++k) a -= Kl[r*17+k]*Hl[k*33+c];
            Wl[r*33+c] = a;
        }
        __syncthreads();
        for (int i = tid; i < S_DIM*S_DIM; i += 256) {
            int r = i >> 5, c = i & 31;
            float a = 0.0f;
            for (int k = 0; k < S_DIM; ++k) a += Wl[r*33+k]*Fl[k*33+c];
            MK[i] = a;
        }
    }
}

// ---------------- Kernel 3: batch recursion, barrier-free, LDS-free ----------
// One batch per 32-lane half-wave; x_{t+1} = M_t x_t + K_t z_t via shuffles.
__global__ __launch_bounds__(256) void batch_kernel(
    const float* __restrict__ state0,  // (B,32)
    const float* __restrict__ meas,    // (B,T,16)
    const float* __restrict__ wsMK,    // (T,1536)
    float* __restrict__ out,           // (B,T,32)
    int T)
{
    const int tid  = threadIdx.x;
    const int lane = tid & 63;
    const int s    = lane & 31;                 // state index
    const int half = (lane >> 5) & 1;           // which batch in the wave
    const long b   = (long)blockIdx.x * 8 + (tid >> 5);  // global batch

    float x = state0[b*S_DIM + s];

    for (int t = 0; t < T; ++t) {
        const float* MKt = wsMK + (long)t * MK_STRIDE;
        // M row s (32 floats) and K row s (16 floats) -> registers (L1-shared)
        const float4* Mv = (const float4*)(MKt + s*32);
        const float4* Kv = (const float4*)(MKt + 1024 + s*16);
        float4 m0 = Mv[0], m1 = Mv[1], m2 = Mv[2], m3 = Mv[3];
        float4 m4 = Mv[4], m5 = Mv[5], m6 = Mv[6], m7 = Mv[7];
        float4 k0 = Kv[0], k1 = Kv[1], k2 = Kv[2], k3 = Kv[3];
        float mr[32] = {m0.x,m0.y,m0.z,m0.w, m1.x,m1.y,m1.z,m1.w,
                        m2.x,m2.y,m2.z,m2.w, m3.x,m3.y,m3.z,m3.w,
                        m4.x,m4.y,m4.z,m4.w, m5.x,m5.y,m5.z,m5.w,
                        m6.x,m6.y,m6.z,m6.w, m7.x,m7.y,m7.z,m7.w};
        float kr[16] = {k0.x,k0.y,k0.z,k0.w, k1.x,k1.y,k1.z,k1.w,
                        k2.x,k2.y,k2.z,k2.w, k3.x,k3.y,k3.z,k3.w};

        // z for this batch: lanes s<16 of each half hold it
        float zmine = 0.f;
        if (s < O_DIM) zmine = meas[(b*T + t)*O_DIM + s];

        const int base = half << 5;   // lane offset of my batch's lane group
        float a0 = 0.f, a1 = 0.f, a2 = 0.f, a3 = 0.f;
        #pragma unroll
        for (int j = 0; j < 32; j += 4) {
            a0 += mr[j+0] * __shfl(x, base + j + 0, 64);
            a1 += mr[j+1] * __shfl(x, base + j + 1, 64);
            a2 += mr[j+2] * __shfl(x, base + j + 2, 64);
            a3 += mr[j+3] * __shfl(x, base + j + 3, 64);
        }
        #pragma unroll
        for (int k = 0; k < 16; k += 4) {
            a0 += kr[k+0] * __shfl(zmine, base + k + 0, 64);
            a1 += kr[k+1] * __shfl(zmine, base + k + 1, 64);
            a2 += kr[k+2] * __shfl(zmine, base + k + 2, 64);
            a3 += kr[k+3] * __shfl(zmine, base + k + 3, 64);
        }
        x = (a0 + a1) + (a2 + a3);
        out[(b*T + t)*S_DIM + s] = x;
    }
}

extern "C" void kernel_launch(void* const* d_in, const int* in_sizes, int n_in,
                              void* d_out, int out_size, void* d_ws, size_t ws_size,
                              hipStream_t stream) {
    const float* state0 = (const float*)d_in[0];
    const float* cov0   = (const float*)d_in[1];
    const float* meas   = (const float*)d_in[2];
    const float* Fm     = (const float*)d_in[3];
    const float* Hm     = (const float*)d_in[4];
    const float* Qm     = (const float*)d_in[5];
    const float* Rm     = (const float*)d_in[6];
    float* out   = (float*)d_out;
    float* wsMK  = (float*)d_ws;

    const int B = in_sizes[0] / S_DIM;               // 2048
    const int T = in_sizes[2] / (B * O_DIM);         // 64

    traj_kernel<<<dim3(1), dim3(256), 0, stream>>>(cov0, Fm, Hm, Qm, Rm, wsMK, T);
    mk_kernel<<<dim3(T), dim3(256), 0, stream>>>(Fm, Hm, wsMK, T);
    batch_kernel<<<dim3(B/8), dim3(256), 0, stream>>>(state0, meas, wsMK, out, T);
}

// Round 6
// 396.072 us; speedup vs baseline: 1.7197x; 1.7197x over previous
//
#include <hip/hip_runtime.h>
#include <math.h>

// Kalman filter. Covariance trajectory (P_t, K_t) is batch-independent.
//   Kernel 1 (traj): 1 block, fp64. Per step: HP=H*Ppred, S=HP*H^T+R (LDS),
//     then Gauss-Jordan on [S | HP] in wave-0 REGISTERS with column ownership:
//     pivot broadcasts via v_readlane (SGPR, no LDS pipe, no barriers).
//     Emits K_t (fp32, 32x16 row-major) to ws. 4 barriers/step (F==I path,
//     Q folded into the P update).
//   Kernel 2 (batch): x' = x + K(z - Hx); one batch per 32-lane half-wave;
//     H rows in registers (loaded once); K/z software-pipelined; shuffles for
//     cross-lane x/innov.

#define S_DIM 32
#define O_DIM 16
#define K_STRIDE 512   // floats per step in ws: K (32x16)

__device__ __forceinline__ double rdlane64(double v, int srcLane) {
    union { double d; unsigned int u[2]; } x; x.d = v;
    unsigned int lo = (unsigned int)__builtin_amdgcn_readlane((int)x.u[0], srcLane);
    unsigned int hi = (unsigned int)__builtin_amdgcn_readlane((int)x.u[1], srcLane);
    union { double d; unsigned int u[2]; } y; y.u[0] = lo; y.u[1] = hi;
    return y.d;
}

// ---------------- Kernel 1: shared trajectory (fp64, 1 block) ----------------
__global__ __launch_bounds__(256) void traj_kernel(
    const float* __restrict__ cov0,  // (B,32,32) -> batch 0
    const float* __restrict__ Fm,    // (32,32)
    const float* __restrict__ Hm,    // (16,32)
    const float* __restrict__ Qm,    // (32,32)
    const float* __restrict__ Rm,    // (16,16)
    float* __restrict__ wsK,         // (T,512)
    int T)
{
    __shared__ double P  [S_DIM*33];
    __shared__ double Fs [S_DIM*33];
    __shared__ double Qs [S_DIM*33];
    __shared__ double Hs [O_DIM*33];
    __shared__ double Rs [O_DIM*17];
    __shared__ double HP [O_DIM*33];
    __shared__ double Sg [O_DIM*17];  // S = HP H^T + R
    __shared__ double KT [O_DIM*33];  // KT[o*33+j] = K[j][o]
    __shared__ double Tp [S_DIM*33];  // general-F predict temp
    __shared__ int notId;

    const int tid = threadIdx.x;

    for (int i = tid; i < S_DIM*S_DIM; i += 256) {
        int r = i >> 5, c = i & 31;
        P [r*33+c] = (double)cov0[i];
        Fs[r*33+c] = (double)Fm[i];
        Qs[r*33+c] = (double)Qm[i];
    }
    for (int i = tid; i < O_DIM*S_DIM; i += 256) {
        int r = i >> 5, c = i & 31;
        Hs[r*33+c] = (double)Hm[i];
    }
    for (int i = tid; i < O_DIM*O_DIM; i += 256) {
        int r = i >> 4, c = i & 15;
        Rs[r*17+c] = (double)Rm[i];
    }
    if (tid == 0) notId = 0;
    __syncthreads();

    {   // F == I detection (block-uniform, deterministic)
        bool bad = false;
        for (int i = tid; i < S_DIM*S_DIM; i += 256) {
            int r = i >> 5, c = i & 31;
            if (Fs[r*33+c] != ((r == c) ? 1.0 : 0.0)) bad = true;
        }
        if (bad) notId = 1;
    }
    __syncthreads();
    const bool fId = (notId == 0);

    // F==I: keep P as P_pred (fold +Q up front; the update phase re-folds).
    if (fId) {
        for (int i = tid; i < S_DIM*S_DIM; i += 256) {
            int r = i >> 5, c = i & 31;
            P[r*33+c] += Qs[r*33+c];
        }
    }
    __syncthreads();

    for (int t = 0; t < T; ++t) {
        // ---- general-F predict: P = F P F^T + Q ----
        if (!fId) {
            for (int i = tid; i < S_DIM*S_DIM; i += 256) {
                int r = i >> 5, c = i & 31;
                double a = 0.0;
                for (int k = 0; k < S_DIM; ++k) a += Fs[r*33+k]*P[k*33+c];
                Tp[r*33+c] = a;
            }
            __syncthreads();
            for (int i = tid; i < S_DIM*S_DIM; i += 256) {
                int r = i >> 5, c = i & 31;
                double a = Qs[r*33+c];
                for (int k = 0; k < S_DIM; ++k) a += Tp[r*33+k]*Fs[c*33+k];
                P[r*33+c] = a;
            }
            __syncthreads();
        }

        // ---- Phase A: HP = H * P_pred (16x32), 2 elems/thread ----
        {
            int i0 = tid, i1 = tid + 256;
            int r0 = i0 >> 5, c0 = i0 & 31;
            int r1 = i1 >> 5, c1 = i1 & 31;
            double a0 = 0.0, a1 = 0.0;
            for (int k = 0; k < S_DIM; ++k) {
                a0 += Hs[r0*33+k]*P[k*33+c0];
                a1 += Hs[r1*33+k]*P[k*33+c1];
            }
            HP[r0*33+c0] = a0;
            HP[r1*33+c1] = a1;
        }
        __syncthreads();

        // ---- Phase B: S = HP H^T + R (16x16), 1 elem/thread ----
        {
            int r = tid >> 4, c = tid & 15;
            double a = Rs[r*17+c];
            for (int k = 0; k < S_DIM; ++k) a += HP[r*33+k]*Hs[c*33+k];
            Sg[r*17+c] = a;
        }
        __syncthreads();

        // ---- Phase C (wave 0): register GJ on [S | HP], column ownership ----
        // Lane c owns column c: c<16 -> S column; c in [16,48) -> HP column.
        if (tid < 64) {
            const int myc = tid;
            const bool isS = (myc < O_DIM);
            const int hc = (myc - O_DIM) & 31;   // clamp for lanes 48..63 (unused)
            double a[16];
            #pragma unroll
            for (int r = 0; r < O_DIM; ++r)
                a[r] = isS ? Sg[r*17+myc] : HP[r*33+hc];

            #pragma unroll
            for (int p = 0; p < O_DIM; ++p) {
                double sp[16];
                #pragma unroll
                for (int r = 0; r < O_DIM; ++r) sp[r] = rdlane64(a[r], p);
                double pinv = 1.0 / sp[p];
                double sc = a[p] * pinv;
                #pragma unroll
                for (int r = 0; r < O_DIM; ++r)
                    a[r] = (r == p) ? sc : fma(-sp[r], sc, a[r]);
            }

            // lanes 16..47 now hold K row j (j = myc-16): a[o] = K[j][o]
            if (!isS && myc < 48) {
                const int j = myc - O_DIM;
                // emit fp32 K row-major
                float4 f0 = make_float4((float)a[0], (float)a[1], (float)a[2], (float)a[3]);
                float4 f1 = make_float4((float)a[4], (float)a[5], (float)a[6], (float)a[7]);
                float4 f2 = make_float4((float)a[8], (float)a[9], (float)a[10],(float)a[11]);
                float4 f3 = make_float4((float)a[12],(float)a[13],(float)a[14],(float)a[15]);
                float4* dst = (float4*)(wsK + (long)t*K_STRIDE + j*O_DIM);
                dst[0] = f0; dst[1] = f1; dst[2] = f2; dst[3] = f3;
                // KT for the P update
                #pragma unroll
                for (int o = 0; o < O_DIM; ++o) KT[o*33+j] = a[o];
            }
        }
        __syncthreads();

        // ---- Phase D: P = P_pred - K*HP (+Q fold for next step if F==I) ----
        for (int i = tid; i < S_DIM*S_DIM; i += 256) {
            int r = i >> 5, c = i & 31;
            double acc = 0.0;
            for (int o = 0; o < O_DIM; ++o) acc += KT[o*33+r]*HP[o*33+c];
            double v = P[r*33+c] - acc;
            if (fId) v += Qs[r*33+c];
            P[r*33+c] = v;
        }
        __syncthreads();
    }
}

// ---------------- Kernel 2: batch recursion, barrier-free, LDS-free ----------
// One batch per 32-lane half-wave; x' = x + K(z - Hx) via shuffles.
__global__ __launch_bounds__(256) void batch_kernel(
    const float* __restrict__ state0,  // (B,32)
    const float* __restrict__ meas,    // (B,T,16)
    const float* __restrict__ wsK,     // (T,512)
    const float* __restrict__ Hm,      // (16,32)
    float* __restrict__ out,           // (B,T,32)
    int T)
{
    const int tid  = threadIdx.x;
    const int lane = tid & 63;
    const int s    = lane & 31;                  // state index
    const int base = lane & 32;                  // lane offset of my batch group
    const long b   = (long)blockIdx.x * 8 + (tid >> 5);

    // H row s (only meaningful for s<16)
    float h[32];
    #pragma unroll
    for (int j = 0; j < 32; ++j) h[j] = 0.f;
    if (s < O_DIM) {
        const float4* Hv = (const float4*)(Hm + s*S_DIM);
        #pragma unroll
        for (int q = 0; q < 8; ++q) {
            float4 v = Hv[q];
            h[q*4+0] = v.x; h[q*4+1] = v.y; h[q*4+2] = v.z; h[q*4+3] = v.w;
        }
    }

    float x = state0[b*S_DIM + s];

    // prefetch step 0
    float4 k0, k1, k2, k3;
    {
        const float4* Kv = (const float4*)(wsK + 0*K_STRIDE + s*O_DIM);
        k0 = Kv[0]; k1 = Kv[1]; k2 = Kv[2]; k3 = Kv[3];
    }
    float z = (s < O_DIM) ? meas[(b*T + 0)*O_DIM + s] : 0.f;

    for (int t = 0; t < T; ++t) {
        // prefetch t+1
        float4 n0, n1, n2, n3; float zn = 0.f;
        if (t + 1 < T) {
            const float4* Kv = (const float4*)(wsK + (long)(t+1)*K_STRIDE + s*O_DIM);
            n0 = Kv[0]; n1 = Kv[1]; n2 = Kv[2]; n3 = Kv[3];
            if (s < O_DIM) zn = meas[(b*T + (t+1))*O_DIM + s];
        } else { n0 = n1 = n2 = n3 = make_float4(0,0,0,0); }

        // y = H x (lanes s<16 meaningful)
        float y0 = 0.f, y1 = 0.f, y2 = 0.f, y3 = 0.f;
        #pragma unroll
        for (int j = 0; j < 32; j += 4) {
            y0 += h[j+0] * __shfl(x, base + j + 0, 64);
            y1 += h[j+1] * __shfl(x, base + j + 1, 64);
            y2 += h[j+2] * __shfl(x, base + j + 2, 64);
            y3 += h[j+3] * __shfl(x, base + j + 3, 64);
        }
        float innov = z - ((y0 + y1) + (y2 + y3));

        float kr[16] = {k0.x,k0.y,k0.z,k0.w, k1.x,k1.y,k1.z,k1.w,
                        k2.x,k2.y,k2.z,k2.w, k3.x,k3.y,k3.z,k3.w};
        float a0 = 0.f, a1 = 0.f, a2 = 0.f, a3 = 0.f;
        #pragma unroll
        for (int o = 0; o < 16; o += 4) {
            a0 += kr[o+0] * __shfl(innov, base + o + 0, 64);
            a1 += kr[o+1] * __shfl(innov, base + o + 1, 64);
            a2 += kr[o+2] * __shfl(innov, base + o + 2, 64);
            a3 += kr[o+3] * __shfl(innov, base + o + 3, 64);
        }
        x = x + ((a0 + a1) + (a2 + a3));
        out[(b*T + t)*S_DIM + s] = x;

        k0 = n0; k1 = n1; k2 = n2; k3 = n3; z = zn;
    }
}

extern "C" void kernel_launch(void* const* d_in, const int* in_sizes, int n_in,
                              void* d_out, int out_size, void* d_ws, size_t ws_size,
                              hipStream_t stream) {
    const float* state0 = (const float*)d_in[0];
    const float* cov0   = (const float*)d_in[1];
    const float* meas   = (const float*)d_in[2];
    const float* Fm     = (const float*)d_in[3];
    const float* Hm     = (const float*)d_in[4];
    const float* Qm     = (const float*)d_in[5];
    const float* Rm     = (const float*)d_in[6];
    float* out  = (float*)d_out;
    float* wsK  = (float*)d_ws;

    const int B = in_sizes[0] / S_DIM;               // 2048
    const int T = in_sizes[2] / (B * O_DIM);         // 64

    traj_kernel<<<dim3(1), dim3(256), 0, stream>>>(cov0, Fm, Hm, Qm, Rm, wsK, T);
    batch_kernel<<<dim3(B/8), dim3(256), 0, stream>>>(state0, meas, wsK, Hm, out, T);
}

// Round 7
// 344.716 us; speedup vs baseline: 1.9759x; 1.1490x over previous
//
#include <hip/hip_runtime.h>
#include <math.h>

// Kalman filter. Covariance trajectory is batch-independent AND (for F==I)
// P never needs materializing:
//   G = S^{-1} HP  (from GJ on [S|HP]);  K = G^T (S, S^{-1} symmetric)
//   HK = H K = (S-R)S^{-1} = I - R S^{-1}  =>  HP_next = R*G + HQ  (HQ const)
// So traj per step = {S = HP H^T + R} -> {GJ} -> {HP update inside GJ wave}.
// 2 barriers/step. General-F fallback keeps the full-P path.
//   Kernel 1 (traj):  1 block, fp64. Emits K_t (fp32) at ws+t*1536+1024.
//   Kernel 2 (mk):    T blocks, M_t = (I - K_t H) F (fp32) at ws+t*1536.
//   Kernel 3 (batch): 1 wave per 2 batches; x' = M x + K z; x via LDS b128;
//     M/K/z per-lane from global (L1 broadcast); software-pipelined.

#define S_DIM 32
#define O_DIM 16
#define MK_STRIDE 1536   // per step: 1024 floats M + 512 floats K

__device__ __forceinline__ double rdlane64(double v, int srcLane) {
    union { double d; unsigned int u[2]; } x; x.d = v;
    unsigned int lo = (unsigned int)__builtin_amdgcn_readlane((int)x.u[0], srcLane);
    unsigned int hi = (unsigned int)__builtin_amdgcn_readlane((int)x.u[1], srcLane);
    union { double d; unsigned int u[2]; } y; y.u[0] = lo; y.u[1] = hi;
    return y.d;
}

// ---------------- Kernel 1: shared trajectory (fp64, 1 block) ----------------
__global__ __launch_bounds__(256) void traj_kernel(
    const float* __restrict__ cov0,  // (B,32,32) -> batch 0
    const float* __restrict__ Fm,    // (32,32)
    const float* __restrict__ Hm,    // (16,32)
    const float* __restrict__ Qm,    // (32,32)
    const float* __restrict__ Rm,    // (16,16)
    float* __restrict__ wsMK,        // (T,1536)
    int T)
{
    __shared__ double P  [S_DIM*33];
    __shared__ double Fs [S_DIM*33];
    __shared__ double Qs [S_DIM*33];
    __shared__ double Tp [S_DIM*33];
    __shared__ double Hs [O_DIM*33];
    __shared__ double HQ [O_DIM*33];
    __shared__ double HPs[O_DIM*33];
    __shared__ double KT [O_DIM*33];
    __shared__ double Sg [O_DIM*17];
    __shared__ double Rs [O_DIM*17];
    __shared__ int notId, notDiag;

    const int tid = threadIdx.x;

    for (int i = tid; i < S_DIM*S_DIM; i += 256) {
        int r = i >> 5, c = i & 31;
        P [r*33+c] = (double)cov0[i];
        Fs[r*33+c] = (double)Fm[i];
        Qs[r*33+c] = (double)Qm[i];
    }
    for (int i = tid; i < O_DIM*S_DIM; i += 256) {
        int r = i >> 5, c = i & 31;
        Hs[r*33+c] = (double)Hm[i];
    }
    for (int i = tid; i < O_DIM*O_DIM; i += 256) {
        int r = i >> 4, c = i & 15;
        Rs[r*17+c] = (double)Rm[i];
    }
    if (tid == 0) { notId = 0; notDiag = 0; }
    __syncthreads();

    {   // F == I and R diagonal detection (block-uniform, deterministic)
        bool badI = false, badD = false;
        for (int i = tid; i < S_DIM*S_DIM; i += 256) {
            int r = i >> 5, c = i & 31;
            if (Fs[r*33+c] != ((r == c) ? 1.0 : 0.0)) badI = true;
        }
        for (int i = tid; i < O_DIM*O_DIM; i += 256) {
            int r = i >> 4, c = i & 15;
            if (r != c && Rs[r*17+c] != 0.0) badD = true;
        }
        if (badI) notId = 1;
        if (badD) notDiag = 1;
    }
    __syncthreads();
    const bool fId   = (notId == 0);
    const bool rDiag = (notDiag == 0);

    if (fId) {   // P_pred_0 = P0 + Q
        for (int i = tid; i < S_DIM*S_DIM; i += 256) {
            int r = i >> 5, c = i & 31;
            P[r*33+c] += Qs[r*33+c];
        }
    }
    __syncthreads();

    if (fId) {   // pre-loop: HP_0 = H*P_pred_0 and HQ = H*Q
        int i0 = tid, i1 = tid + 256;
        int r0 = i0 >> 5, c0 = i0 & 31;
        int r1 = i1 >> 5, c1 = i1 & 31;
        double a0 = 0.0, a1 = 0.0, q0 = 0.0, q1 = 0.0;
        for (int k = 0; k < S_DIM; ++k) {
            a0 += Hs[r0*33+k]*P [k*33+c0];
            a1 += Hs[r1*33+k]*P [k*33+c1];
            q0 += Hs[r0*33+k]*Qs[k*33+c0];
            q1 += Hs[r1*33+k]*Qs[k*33+c1];
        }
        HPs[r0*33+c0] = a0;  HPs[r1*33+c1] = a1;
        HQ [r0*33+c0] = q0;  HQ [r1*33+c1] = q1;
    }
    __syncthreads();

    for (int t = 0; t < T; ++t) {
        if (!fId) {
            // predict: P = F P F^T + Q
            for (int i = tid; i < S_DIM*S_DIM; i += 256) {
                int r = i >> 5, c = i & 31;
                double a = 0.0;
                for (int k = 0; k < S_DIM; ++k) a += Fs[r*33+k]*P[k*33+c];
                Tp[r*33+c] = a;
            }
            __syncthreads();
            for (int i = tid; i < S_DIM*S_DIM; i += 256) {
                int r = i >> 5, c = i & 31;
                double a = Qs[r*33+c];
                for (int k = 0; k < S_DIM; ++k) a += Tp[r*33+k]*Fs[c*33+k];
                P[r*33+c] = a;
            }
            __syncthreads();
            // HP = H * P_pred
            int i0 = tid, i1 = tid + 256;
            int r0 = i0 >> 5, c0 = i0 & 31;
            int r1 = i1 >> 5, c1 = i1 & 31;
            double a0 = 0.0, a1 = 0.0;
            for (int k = 0; k < S_DIM; ++k) {
                a0 += Hs[r0*33+k]*P[k*33+c0];
                a1 += Hs[r1*33+k]*P[k*33+c1];
            }
            HPs[r0*33+c0] = a0;
            HPs[r1*33+c1] = a1;
            __syncthreads();
        }

        // ---- S = HP H^T + R (16x16), 1 elem/thread ----
        {
            int r = tid >> 4, c = tid & 15;
            double a = Rs[r*17+c];
            for (int k = 0; k < S_DIM; ++k) a += HPs[r*33+k]*Hs[c*33+k];
            Sg[r*17+c] = a;
        }
        __syncthreads();

        // ---- wave 0: register GJ on [S | HP] -> G = S^{-1} HP; K = G^T;
        //      for F==I also HP_next = R*G + HQ written here ----
        if (tid < 64) {
            const int myc = tid;
            const bool isS = (myc < O_DIM);
            const int hc = (myc - O_DIM) & 31;
            double a[16];
            #pragma unroll
            for (int r = 0; r < O_DIM; ++r)
                a[r] = isS ? Sg[r*17+myc] : HPs[r*33+hc];

            #pragma unroll
            for (int p = 0; p < O_DIM; ++p) {
                double sp[16];
                #pragma unroll
                for (int r = 0; r < O_DIM; ++r) sp[r] = rdlane64(a[r], p);
                double pinv = 1.0 / sp[p];
                double sc = a[p] * pinv;
                #pragma unroll
                for (int r = 0; r < O_DIM; ++r)
                    a[r] = (r == p) ? sc : fma(-sp[r], sc, a[r]);
            }

            if (!isS && myc < 48) {
                const int j = myc - O_DIM;   // state index (K row / HP col)
                // emit fp32 K row j
                float4 f0 = make_float4((float)a[0], (float)a[1], (float)a[2], (float)a[3]);
                float4 f1 = make_float4((float)a[4], (float)a[5], (float)a[6], (float)a[7]);
                float4 f2 = make_float4((float)a[8], (float)a[9], (float)a[10],(float)a[11]);
                float4 f3 = make_float4((float)a[12],(float)a[13],(float)a[14],(float)a[15]);
                float4* dst = (float4*)(wsMK + (long)t*MK_STRIDE + 1024 + j*O_DIM);
                dst[0] = f0; dst[1] = f1; dst[2] = f2; dst[3] = f3;

                if (fId) {
                    // HP_next[:, j] = (R*G)[:, j] + HQ[:, j]
                    if (rDiag) {
                        #pragma unroll
                        for (int r = 0; r < O_DIM; ++r)
                            HPs[r*33+j] = Rs[r*17+r]*a[r] + HQ[r*33+j];
                    } else {
                        #pragma unroll
                        for (int r = 0; r < O_DIM; ++r) {
                            double rg = 0.0;
                            for (int k = 0; k < O_DIM; ++k) rg += Rs[r*17+k]*a[k];
                            HPs[r*33+j] = rg + HQ[r*33+j];
                        }
                    }
                } else {
                    #pragma unroll
                    for (int o = 0; o < O_DIM; ++o) KT[o*33+j] = a[o];
                }
            }
        }
        __syncthreads();

        if (!fId) {
            // P = P_pred - K*HP
            for (int i = tid; i < S_DIM*S_DIM; i += 256) {
                int r = i >> 5, c = i & 31;
                double acc = 0.0;
                for (int o = 0; o < O_DIM; ++o) acc += KT[o*33+r]*HPs[o*33+c];
                P[r*33+c] -= acc;
            }
            __syncthreads();
        }
    }
}

// ---------------- Kernel 2: M_t = (I - K_t H) F, fp32, T blocks ----------------
__global__ __launch_bounds__(256) void mk_kernel(
    const float* __restrict__ Fm,    // (32,32)
    const float* __restrict__ Hm,    // (16,32)
    float* __restrict__ wsMK,        // (T,1536): K at +1024 (in), M at +0 (out)
    int T)
{
    __shared__ float Kl[S_DIM*17];
    __shared__ float Hl[O_DIM*33];
    __shared__ float Fl[S_DIM*33];
    __shared__ float Wl[S_DIM*33];
    __shared__ int notId;

    const int tid = threadIdx.x;
    const int t   = blockIdx.x;
    float* MK = wsMK + (long)t * MK_STRIDE;

    for (int i = tid; i < S_DIM*O_DIM; i += 256)
        Kl[(i >> 4)*17 + (i & 15)] = MK[1024 + i];
    for (int i = tid; i < O_DIM*S_DIM; i += 256)
        Hl[(i >> 5)*33 + (i & 31)] = Hm[i];
    for (int i = tid; i < S_DIM*S_DIM; i += 256)
        Fl[(i >> 5)*33 + (i & 31)] = Fm[i];
    if (tid == 0) notId = 0;
    __syncthreads();
    {
        bool bad = false;
        for (int i = tid; i < S_DIM*S_DIM; i += 256) {
            int r = i >> 5, c = i & 31;
            if (Fl[r*33+c] != ((r == c) ? 1.0f : 0.0f)) bad = true;
        }
        if (bad) notId = 1;
    }
    __syncthreads();
    const bool fId = (notId == 0);

    if (fId) {
        for (int i = tid; i < S_DIM*S_DIM; i += 256) {
            int r = i >> 5, c = i & 31;
            float a = (r == c) ? 1.0f : 0.0f;
            for (int k = 0; k < O_DIM; ++k) a -= Kl[r*17+k]*Hl[k*33+c];
            MK[i] = a;
        }
    } else {
        for (int i = tid; i < S_DIM*S_DIM; i += 256) {
            int r = i >> 5, c = i & 31;
            float a = (r == c) ? 1.0f : 0.0f;
            for (int k = 0; k < O_DIM; ++k) a -= Kl[r*17+k]*Hl[k*33+c];
            Wl[r*33+c] = a;
        }
        __syncthreads();
        for (int i = tid; i < S_DIM*S_DIM; i += 256) {
            int r = i >> 5, c = i & 31;
            float a = 0.0f;
            for (int k = 0; k < S_DIM; ++k) a += Wl[r*33+k]*Fl[k*33+c];
            MK[i] = a;
        }
    }
}

// ---------------- Kernel 3: batch recursion, 1 wave / 2 batches --------------
// x' = M x + K z. x exchanged via LDS (1 write + 8 b128 reads per step);
// M/K rows and z fetched per-lane from global (L1-broadcast). Pipelined.
__global__ __launch_bounds__(64) void batch_kernel(
    const float* __restrict__ state0,  // (B,32)
    const float* __restrict__ meas,    // (B,T,16)
    const float* __restrict__ wsMK,    // (T,1536)
    float* __restrict__ out,           // (B,T,32)
    int T)
{
    const int lane = threadIdx.x;
    const int s    = lane & 31;
    const int half = lane >> 5;
    const long b   = (long)blockIdx.x * 2 + half;

    __shared__ float xs[2][32];

    float x = state0[b*S_DIM + s];
    xs[half][s] = x;
    __syncthreads();

    float4 m[8], k4[4], z4[4];
    {
        const float4* Mv = (const float4*)(wsMK + 0*MK_STRIDE + s*S_DIM);
        #pragma unroll
        for (int q = 0; q < 8; ++q) m[q] = Mv[q];
        const float4* Kv = (const float4*)(wsMK + 0*MK_STRIDE + 1024 + s*O_DIM);
        #pragma unroll
        for (int q = 0; q < 4; ++q) k4[q] = Kv[q];
        const float4* Zv = (const float4*)(meas + (b*T + 0)*O_DIM);
        #pragma unroll
        for (int q = 0; q < 4; ++q) z4[q] = Zv[q];
    }

    for (int t = 0; t < T; ++t) {
        // prefetch t+1 (clamped; unused values on last iter)
        float4 mn[8], kn[4], zn[4];
        {
            const int tn = (t + 1 < T) ? (t + 1) : t;
            const float4* Mv = (const float4*)(wsMK + (long)tn*MK_STRIDE + s*S_DIM);
            #pragma unroll
            for (int q = 0; q < 8; ++q) mn[q] = Mv[q];
            const float4* Kv = (const float4*)(wsMK + (long)tn*MK_STRIDE + 1024 + s*O_DIM);
            #pragma unroll
            for (int q = 0; q < 4; ++q) kn[q] = Kv[q];
            const float4* Zv = (const float4*)(meas + (b*T + tn)*O_DIM);
            #pragma unroll
            for (int q = 0; q < 4; ++q) zn[q] = Zv[q];
        }

        // x' = M x + K z
        const float4* xv = (const float4*)(&xs[half][0]);
        float a0 = 0.f, a1 = 0.f, a2 = 0.f, a3 = 0.f;
        #pragma unroll
        for (int q = 0; q < 8; ++q) {
            float4 xq = xv[q];
            a0 += m[q].x * xq.x;
            a1 += m[q].y * xq.y;
            a2 += m[q].z * xq.z;
            a3 += m[q].w * xq.w;
        }
        #pragma unroll
        for (int q = 0; q < 4; ++q) {
            a0 += k4[q].x * z4[q].x;
            a1 += k4[q].y * z4[q].y;
            a2 += k4[q].z * z4[q].z;
            a3 += k4[q].w * z4[q].w;
        }
        float xnew = (a0 + a1) + (a2 + a3);
        out[(b*T + t)*S_DIM + s] = xnew;

        __syncthreads();           // all b128 reads of xs done
        xs[half][s] = xnew;
        __syncthreads();           // write visible before next reads

        #pragma unroll
        for (int q = 0; q < 8; ++q) m[q] = mn[q];
        #pragma unroll
        for (int q = 0; q < 4; ++q) { k4[q] = kn[q]; z4[q] = zn[q]; }
    }
}

extern "C" void kernel_launch(void* const* d_in, const int* in_sizes, int n_in,
                              void* d_out, int out_size, void* d_ws, size_t ws_size,
                              hipStream_t stream) {
    const float* state0 = (const float*)d_in[0];
    const float* cov0   = (const float*)d_in[1];
    const float* meas   = (const float*)d_in[2];
    const float* Fm     = (const float*)d_in[3];
    const float* Hm     = (const float*)d_in[4];
    const float* Qm     = (const float*)d_in[5];
    const float* Rm     = (const float*)d_in[6];
    float* out   = (float*)d_out;
    float* wsMK  = (float*)d_ws;

    const int B = in_sizes[0] / S_DIM;               // 2048
    const int T = in_sizes[2] / (B * O_DIM);         // 64

    traj_kernel<<<dim3(1), dim3(256), 0, stream>>>(cov0, Fm, Hm, Qm, Rm, wsMK, T);
    mk_kernel<<<dim3(T), dim3(256), 0, stream>>>(Fm, Hm, wsMK, T);
    batch_kernel<<<dim3(B/2), dim3(64), 0, stream>>>(state0, meas, wsMK, out, T);
}

// Round 8
// 338.640 us; speedup vs baseline: 2.0114x; 1.0179x over previous
//
#include <hip/hip_runtime.h>
#include <math.h>

// Kalman filter. Covariance trajectory is batch-independent AND (for F==I)
// P never materialized:
//   G = S^{-1} HP (GJ on [S|HP]); K = G^T; HP_next = R*G + HQ (HQ = H*Q const)
// traj per step = {S = HP H^T + R} -> {register GJ, wave 0} -> {HP update}.
//   Kernel 1 (traj):  1 block, fp64, 2 barriers/step. Emits K_t (fp32).
//   Kernel 2 (mk):    T blocks, M_t = (I - K_t H) F (fp32).
//   Kernel 3 (batch): ONE WAVE PER BATCH, split-dot (half-rows per lane pair),
//     combine via shfl_xor(32); x via LDS b128; no barriers; prefetched.

#define S_DIM 32
#define O_DIM 16
#define MK_STRIDE 1536   // per step: 1024 floats M + 512 floats K
#define HS 34            // padded stride (even -> 16B aligned rows) for 16x32 fp64

__device__ __forceinline__ double rdlane64(double v, int srcLane) {
    union { double d; unsigned int u[2]; } x; x.d = v;
    unsigned int lo = (unsigned int)__builtin_amdgcn_readlane((int)x.u[0], srcLane);
    unsigned int hi = (unsigned int)__builtin_amdgcn_readlane((int)x.u[1], srcLane);
    union { double d; unsigned int u[2]; } y; y.u[0] = lo; y.u[1] = hi;
    return y.d;
}

// ---------------- Kernel 1: shared trajectory (fp64, 1 block) ----------------
__global__ __launch_bounds__(256) void traj_kernel(
    const float* __restrict__ cov0,  // (B,32,32) -> batch 0
    const float* __restrict__ Fm,    // (32,32)
    const float* __restrict__ Hm,    // (16,32)
    const float* __restrict__ Qm,    // (32,32)
    const float* __restrict__ Rm,    // (16,16)
    float* __restrict__ wsMK,        // (T,1536)
    int T)
{
    __shared__ double P  [S_DIM*33];
    __shared__ double Fs [S_DIM*33];
    __shared__ double Qs [S_DIM*33];
    __shared__ double Tp [S_DIM*33];
    __shared__ double Hs [O_DIM*HS];
    __shared__ double HQ [O_DIM*HS];
    __shared__ double HPs[O_DIM*HS];
    __shared__ double KT [O_DIM*33];
    __shared__ double Sg [O_DIM*17];
    __shared__ double Rs [O_DIM*17];
    __shared__ int notId, notDiag;

    const int tid = threadIdx.x;

    for (int i = tid; i < S_DIM*S_DIM; i += 256) {
        int r = i >> 5, c = i & 31;
        P [r*33+c] = (double)cov0[i];
        Fs[r*33+c] = (double)Fm[i];
        Qs[r*33+c] = (double)Qm[i];
    }
    for (int i = tid; i < O_DIM*S_DIM; i += 256) {
        int r = i >> 5, c = i & 31;
        Hs[r*HS+c] = (double)Hm[i];
    }
    for (int i = tid; i < O_DIM*O_DIM; i += 256) {
        int r = i >> 4, c = i & 15;
        Rs[r*17+c] = (double)Rm[i];
    }
    if (tid == 0) { notId = 0; notDiag = 0; }
    __syncthreads();

    {   // F == I and R-diagonal detection (block-uniform, deterministic)
        bool badI = false, badD = false;
        for (int i = tid; i < S_DIM*S_DIM; i += 256) {
            int r = i >> 5, c = i & 31;
            if (Fs[r*33+c] != ((r == c) ? 1.0 : 0.0)) badI = true;
        }
        for (int i = tid; i < O_DIM*O_DIM; i += 256) {
            int r = i >> 4, c = i & 15;
            if (r != c && Rs[r*17+c] != 0.0) badD = true;
        }
        if (badI) notId = 1;
        if (badD) notDiag = 1;
    }
    __syncthreads();
    const bool fId   = (notId == 0);
    const bool rDiag = (notDiag == 0);

    if (fId) {
        for (int i = tid; i < S_DIM*S_DIM; i += 256) {
            int r = i >> 5, c = i & 31;
            P[r*33+c] += Qs[r*33+c];
        }
    }
    __syncthreads();

    if (fId) {   // HP_0 = H*P_pred_0; HQ = H*Q
        int i0 = tid, i1 = tid + 256;
        int r0 = i0 >> 5, c0 = i0 & 31;
        int r1 = i1 >> 5, c1 = i1 & 31;
        double a0 = 0.0, a1 = 0.0, q0 = 0.0, q1 = 0.0;
        for (int k = 0; k < S_DIM; ++k) {
            a0 += Hs[r0*HS+k]*P [k*33+c0];
            a1 += Hs[r1*HS+k]*P [k*33+c1];
            q0 += Hs[r0*HS+k]*Qs[k*33+c0];
            q1 += Hs[r1*HS+k]*Qs[k*33+c1];
        }
        HPs[r0*HS+c0] = a0;  HPs[r1*HS+c1] = a1;
        HQ [r0*HS+c0] = q0;  HQ [r1*HS+c1] = q1;
    }
    __syncthreads();

    for (int t = 0; t < T; ++t) {
        if (!fId) {
            // predict: P = F P F^T + Q, then HP = H P
            for (int i = tid; i < S_DIM*S_DIM; i += 256) {
                int r = i >> 5, c = i & 31;
                double a = 0.0;
                for (int k = 0; k < S_DIM; ++k) a += Fs[r*33+k]*P[k*33+c];
                Tp[r*33+c] = a;
            }
            __syncthreads();
            for (int i = tid; i < S_DIM*S_DIM; i += 256) {
                int r = i >> 5, c = i & 31;
                double a = Qs[r*33+c];
                for (int k = 0; k < S_DIM; ++k) a += Tp[r*33+k]*Fs[c*33+k];
                P[r*33+c] = a;
            }
            __syncthreads();
            int i0 = tid, i1 = tid + 256;
            int r0 = i0 >> 5, c0 = i0 & 31;
            int r1 = i1 >> 5, c1 = i1 & 31;
            double a0 = 0.0, a1 = 0.0;
            for (int k = 0; k < S_DIM; ++k) {
                a0 += Hs[r0*HS+k]*P[k*33+c0];
                a1 += Hs[r1*HS+k]*P[k*33+c1];
            }
            HPs[r0*HS+c0] = a0;
            HPs[r1*HS+c1] = a1;
            __syncthreads();
        }

        // ---- S = HP H^T + R (16x16), 1 elem/thread, double2 reads ----
        {
            int r = tid >> 4, c = tid & 15;
            double a = Rs[r*17+c];
            const double2* hp = (const double2*)&HPs[r*HS];
            const double2* hh = (const double2*)&Hs [c*HS];
            #pragma unroll
            for (int k = 0; k < 16; ++k) {
                double2 u = hp[k], v = hh[k];
                a += u.x*v.x + u.y*v.y;
            }
            Sg[r*17+c] = a;
        }
        __syncthreads();

        // ---- wave 0: register GJ on [S | HP] -> G = S^{-1} HP; K = G^T;
        //      F==I: HP_next = R*G + HQ written here ----
        if (tid < 64) {
            const int myc = tid;
            const bool isS = (myc < O_DIM);
            const int hc = (myc - O_DIM) & 31;
            double a[16];
            #pragma unroll
            for (int r = 0; r < O_DIM; ++r)
                a[r] = isS ? Sg[r*17+myc] : HPs[r*HS+hc];

            #pragma unroll
            for (int p = 0; p < O_DIM; ++p) {
                double sp[16];
                #pragma unroll
                for (int r = 0; r < O_DIM; ++r) sp[r] = rdlane64(a[r], p);
                double pinv = 1.0 / sp[p];
                double sc = a[p] * pinv;
                #pragma unroll
                for (int r = 0; r < O_DIM; ++r)
                    a[r] = (r == p) ? sc : fma(-sp[r], sc, a[r]);
            }

            if (!isS && myc < 48) {
                const int j = myc - O_DIM;   // state index (K row / HP col)
                float4 f0 = make_float4((float)a[0], (float)a[1], (float)a[2], (float)a[3]);
                float4 f1 = make_float4((float)a[4], (float)a[5], (float)a[6], (float)a[7]);
                float4 f2 = make_float4((float)a[8], (float)a[9], (float)a[10],(float)a[11]);
                float4 f3 = make_float4((float)a[12],(float)a[13],(float)a[14],(float)a[15]);
                float4* dst = (float4*)(wsMK + (long)t*MK_STRIDE + 1024 + j*O_DIM);
                dst[0] = f0; dst[1] = f1; dst[2] = f2; dst[3] = f3;

                if (fId) {
                    if (rDiag) {
                        #pragma unroll
                        for (int r = 0; r < O_DIM; ++r)
                            HPs[r*HS+j] = Rs[r*17+r]*a[r] + HQ[r*HS+j];
                    } else {
                        #pragma unroll
                        for (int r = 0; r < O_DIM; ++r) {
                            double rg = 0.0;
                            for (int k = 0; k < O_DIM; ++k) rg += Rs[r*17+k]*a[k];
                            HPs[r*HS+j] = rg + HQ[r*HS+j];
                        }
                    }
                } else {
                    #pragma unroll
                    for (int o = 0; o < O_DIM; ++o) KT[o*33+j] = a[o];
                }
            }
        }
        __syncthreads();

        if (!fId) {
            for (int i = tid; i < S_DIM*S_DIM; i += 256) {
                int r = i >> 5, c = i & 31;
                double acc = 0.0;
                for (int o = 0; o < O_DIM; ++o) acc += KT[o*33+r]*HPs[o*HS+c];
                P[r*33+c] -= acc;
            }
            __syncthreads();
        }
    }
}

// ---------------- Kernel 2: M_t = (I - K_t H) F, fp32, T blocks ----------------
__global__ __launch_bounds__(256) void mk_kernel(
    const float* __restrict__ Fm,    // (32,32)
    const float* __restrict__ Hm,    // (16,32)
    float* __restrict__ wsMK,        // (T,1536): K at +1024 (in), M at +0 (out)
    int T)
{
    __shared__ float Kl[S_DIM*17];
    __shared__ float Hl[O_DIM*33];
    __shared__ float Fl[S_DIM*33];
    __shared__ float Wl[S_DIM*33];
    __shared__ int notId;

    const int tid = threadIdx.x;
    const int t   = blockIdx.x;
    float* MK = wsMK + (long)t * MK_STRIDE;

    for (int i = tid; i < S_DIM*O_DIM; i += 256)
        Kl[(i >> 4)*17 + (i & 15)] = MK[1024 + i];
    for (int i = tid; i < O_DIM*S_DIM; i += 256)
        Hl[(i >> 5)*33 + (i & 31)] = Hm[i];
    for (int i = tid; i < S_DIM*S_DIM; i += 256)
        Fl[(i >> 5)*33 + (i & 31)] = Fm[i];
    if (tid == 0) notId = 0;
    __syncthreads();
    {
        bool bad = false;
        for (int i = tid; i < S_DIM*S_DIM; i += 256) {
            int r = i >> 5, c = i & 31;
            if (Fl[r*33+c] != ((r == c) ? 1.0f : 0.0f)) bad = true;
        }
        if (bad) notId = 1;
    }
    __syncthreads();
    const bool fId = (notId == 0);

    if (fId) {
        for (int i = tid; i < S_DIM*S_DIM; i += 256) {
            int r = i >> 5, c = i & 31;
            float a = (r == c) ? 1.0f : 0.0f;
            for (int k = 0; k < O_DIM; ++k) a -= Kl[r*17+k]*Hl[k*33+c];
            MK[i] = a;
        }
    } else {
        for (int i = tid; i < S_DIM*S_DIM; i += 256) {
            int r = i >> 5, c = i & 31;
            float a = (r == c) ? 1.0f : 0.0f;
            for (int k = 0; k < O_DIM; ++k) a -= Kl[r*17+k]*Hl[k*33+c];
            Wl[r*33+c] = a;
        }
        __syncthreads();
        for (int i = tid; i < S_DIM*S_DIM; i += 256) {
            int r = i >> 5, c = i & 31;
            float a = 0.0f;
            for (int k = 0; k < S_DIM; ++k) a += Wl[r*33+k]*Fl[k*33+c];
            MK[i] = a;
        }
    }
}

// ---------------- Kernel 3: batch recursion, ONE WAVE PER BATCH --------------
// Lane (s, h): partial dot over j in [16h,16h+16) (M) and o in [8h,8h+8) (K);
// combine halves via __shfl_xor(32). x exchanged via LDS (in-order DS pipe,
// single wave -> no barriers). Software-pipelined loads.
__global__ __launch_bounds__(64) void batch_kernel(
    const float* __restrict__ state0,  // (B,32)
    const float* __restrict__ meas,    // (B,T,16)
    const float* __restrict__ wsMK,    // (T,1536)
    float* __restrict__ out,           // (B,T,32)
    int T)
{
    const int lane = threadIdx.x;      // 0..63
    const int s    = lane & 31;
    const int h    = lane >> 5;        // which half of the dot
    const long b   = blockIdx.x;       // one batch per wave

    __shared__ float xs[32];

    if (h == 0) xs[s] = state0[b*S_DIM + s];
    __syncthreads();   // once

    // prefetch step 0: M[s][16h..16h+16), K[s][8h..8h+8), z[8h..8h+8)
    float4 m[4], k2[2], z2[2];
    {
        const float4* Mv = (const float4*)(wsMK + 0*MK_STRIDE + s*S_DIM + h*16);
        m[0]=Mv[0]; m[1]=Mv[1]; m[2]=Mv[2]; m[3]=Mv[3];
        const float4* Kv = (const float4*)(wsMK + 0*MK_STRIDE + 1024 + s*O_DIM + h*8);
        k2[0]=Kv[0]; k2[1]=Kv[1];
        const float4* Zv = (const float4*)(meas + (b*T + 0)*O_DIM + h*8);
        z2[0]=Zv[0]; z2[1]=Zv[1];
    }

    for (int t = 0; t < T; ++t) {
        // prefetch t+1 (clamped)
        float4 mn[4], kn[2], zn[2];
        {
            const int tn = (t + 1 < T) ? (t + 1) : t;
            const float4* Mv = (const float4*)(wsMK + (long)tn*MK_STRIDE + s*S_DIM + h*16);
            mn[0]=Mv[0]; mn[1]=Mv[1]; mn[2]=Mv[2]; mn[3]=Mv[3];
            const float4* Kv = (const float4*)(wsMK + (long)tn*MK_STRIDE + 1024 + s*O_DIM + h*8);
            kn[0]=Kv[0]; kn[1]=Kv[1];
            const float4* Zv = (const float4*)(meas + (b*T + tn)*O_DIM + h*8);
            zn[0]=Zv[0]; zn[1]=Zv[1];
        }

        // my half of x: x[16h .. 16h+16)
        const float4* xv = (const float4*)(&xs[h*16]);
        float4 x0 = xv[0], x1 = xv[1], x2 = xv[2], x3 = xv[3];

        float a0 = m[0].x*x0.x + m[0].y*x0.y + m[0].z*x0.z + m[0].w*x0.w;
        float a1 = m[1].x*x1.x + m[1].y*x1.y + m[1].z*x1.z + m[1].w*x1.w;
        float a2 = m[2].x*x2.x + m[2].y*x2.y + m[2].z*x2.z + m[2].w*x2.w;
        float a3 = m[3].x*x3.x + m[3].y*x3.y + m[3].z*x3.z + m[3].w*x3.w;
        a0 += k2[0].x*z2[0].x + k2[0].y*z2[0].y + k2[0].z*z2[0].z + k2[0].w*z2[0].w;
        a1 += k2[1].x*z2[1].x + k2[1].y*z2[1].y + k2[1].z*z2[1].z + k2[1].w*z2[1].w;
        float part = (a0 + a1) + (a2 + a3);

        // combine halves: xnew valid in both lanes s and s+32
        float xnew = part + __shfl_xor(part, 32, 64);

        if (h == 0) out[(b*T + t)*S_DIM + s] = xnew;

        __builtin_amdgcn_wave_barrier();   // keep xs reads above the write
        if (h == 0) xs[s] = xnew;
        __builtin_amdgcn_wave_barrier();   // keep next reads below the write

        m[0]=mn[0]; m[1]=mn[1]; m[2]=mn[2]; m[3]=mn[3];
        k2[0]=kn[0]; k2[1]=kn[1];
        z2[0]=zn[0]; z2[1]=zn[1];
    }
}

extern "C" void kernel_launch(void* const* d_in, const int* in_sizes, int n_in,
                              void* d_out, int out_size, void* d_ws, size_t ws_size,
                              hipStream_t stream) {
    const float* state0 = (const float*)d_in[0];
    const float* cov0   = (const float*)d_in[1];
    const float* meas   = (const float*)d_in[2];
    const float* Fm     = (const float*)d_in[3];
    const float* Hm     = (const float*)d_in[4];
    const float* Qm     = (const float*)d_in[5];
    const float* Rm     = (const float*)d_in[6];
    float* out   = (float*)d_out;
    float* wsMK  = (float*)d_ws;

    const int B = in_sizes[0] / S_DIM;               // 2048
    const int T = in_sizes[2] / (B * O_DIM);         // 64

    traj_kernel<<<dim3(1), dim3(256), 0, stream>>>(cov0, Fm, Hm, Qm, Rm, wsMK, T);
    mk_kernel<<<dim3(T), dim3(256), 0, stream>>>(Fm, Hm, wsMK, T);
    batch_kernel<<<dim3(B), dim3(64), 0, stream>>>(state0, meas, wsMK, out, T);
}